// Round 6
// baseline (735.380 us; speedup 1.0000x reference)
//
#include <hip/hip_runtime.h>

#define N_ATOMS 100000
#define N_PAIRS 3200000
#define N_PROP 16
#define N_BASIS 10
#define W 16
#define NSUP (N_PAIRS / 32)   // 100000 2-tile supers (32 pairs each)
#define SCAN_BLK 1024
#define NB ((N_ATOMS + SCAN_BLK - 1) / SCAN_BLK)   // 98
#define SC 2.88539008177792681f   // 2*log2(e), folded into weights/pre-acts

typedef short  s16x8 __attribute__((ext_vector_type(8)));
typedef float  f32x4 __attribute__((ext_vector_type(4)));

// tanh with pre-scaled input: y = SC*x  ->  tanh(x) = 1 - 2/(exp2(y)+1)
__device__ __forceinline__ float tanh_pre(float y) {
    float e = __builtin_amdgcn_exp2f(y);
    return 1.0f - 2.0f * __builtin_amdgcn_rcpf(e + 1.0f);
}
__device__ __forceinline__ float fast_tanh(float x) {
    float e = __builtin_amdgcn_exp2f(x * SC);
    return 1.0f - 2.0f * __builtin_amdgcn_rcpf(e + 1.0f);
}
__device__ __forceinline__ unsigned short bf16r(float f) {
    union { float f; unsigned u; } v; v.f = f;
    unsigned r = v.u + 0x7FFFu + ((v.u >> 16) & 1u);
    return (unsigned short)(r >> 16);
}
__device__ __forceinline__ unsigned cvt_pk_bf16(float a, float b) {
    unsigned r;
    asm("v_cvt_pk_bf16_f32 %0, %1, %2" : "=v"(r) : "v"(a), "v"(b));
    return r;   // low16 = bf16(a), high16 = bf16(b), RTNE
}
__device__ __forceinline__ float bitf(unsigned u) {
    union { unsigned u; float f; } v; v.u = u; return v.f;
}

// ---------------- pp_pre: p1_in + fused pi0 per-atom halves
// ytop[a] = SC*(Wpi0_top^T p1_in[a] + bpi0),  ybot[a] = SC*(Wpi0_bot^T p1_in[a])
__global__ __launch_bounds__(256) void k_pp_pre(
    const float* __restrict__ p1,
    const float* __restrict__ W0, const float* __restrict__ b0,
    const float* __restrict__ W1, const float* __restrict__ b1,
    const float* __restrict__ Wpi0, const float* __restrict__ bpi0,
    float* __restrict__ ytop, float* __restrict__ ybot)
{
    int a = blockIdx.x * 256 + threadIdx.x;
    if (a >= N_ATOMS) return;
    const float4* src = reinterpret_cast<const float4*>(p1 + (size_t)a * N_PROP);
    float4 v0 = src[0], v1 = src[1], v2 = src[2], v3 = src[3];
    float x[N_PROP] = {v0.x,v0.y,v0.z,v0.w, v1.x,v1.y,v1.z,v1.w,
                       v2.x,v2.y,v2.z,v2.w, v3.x,v3.y,v3.z,v3.w};
    float h[W];
#pragma unroll
    for (int c = 0; c < W; ++c) h[c] = b0[c];
#pragma unroll
    for (int k = 0; k < N_PROP; ++k)
#pragma unroll
        for (int c = 0; c < W; ++c) h[c] += x[k] * W0[k*W + c];
#pragma unroll
    for (int c = 0; c < W; ++c) h[c] = fast_tanh(h[c]);
    float y[W];
#pragma unroll
    for (int c = 0; c < W; ++c) y[c] = b1[c];
#pragma unroll
    for (int k = 0; k < W; ++k)
#pragma unroll
        for (int c = 0; c < W; ++c) y[c] += h[k] * W1[k*W + c];
    float t[W];
#pragma unroll
    for (int c = 0; c < W; ++c) t[c] = fast_tanh(y[c]);

    float yt[W], yb[W];
#pragma unroll
    for (int c = 0; c < W; ++c) { yt[c] = bpi0[c]; yb[c] = 0.0f; }
#pragma unroll
    for (int k = 0; k < W; ++k)
#pragma unroll
        for (int c = 0; c < W; ++c) {
            yt[c] += t[k] * Wpi0[k*W + c];
            yb[c] += t[k] * Wpi0[(W + k)*W + c];
        }
    float4* dt = reinterpret_cast<float4*>(ytop + (size_t)a * W);
    float4* db = reinterpret_cast<float4*>(ybot + (size_t)a * W);
#pragma unroll
    for (int q = 0; q < 4; ++q) {
        dt[q] = make_float4(SC*yt[4*q], SC*yt[4*q+1], SC*yt[4*q+2], SC*yt[4*q+3]);
        db[q] = make_float4(SC*yb[4*q], SC*yb[4*q+1], SC*yb[4*q+2], SC*yb[4*q+3]);
    }
}

// C-layout x[i] = value for ch 4g+i, pair r at lane (r,g)  ->  B-frag (k=8g'+j), hi/lo.
__device__ __forceinline__ void make_B_hilo(const float x[4], int idxA, int idxB,
                                            int g, bool augment, s16x8& Bh, s16x8& Bl)
{
    unsigned w0h = cvt_pk_bf16(x[0], x[1]);
    unsigned w1h = cvt_pk_bf16(x[2], x[3]);
    float f0 = bitf(w0h << 16), f1 = bitf(w0h & 0xFFFF0000u);
    float f2 = bitf(w1h << 16), f3 = bitf(w1h & 0xFFFF0000u);
    unsigned w0l = cvt_pk_bf16(x[0] - f0, x[1] - f1);
    unsigned w1l = cvt_pk_bf16(x[2] - f2, x[3] - f3);
    union { unsigned u[4]; s16x8 v; } H, L;
    H.u[0] = (unsigned)__shfl((int)w0h, idxA); H.u[1] = (unsigned)__shfl((int)w1h, idxA);
    H.u[2] = (unsigned)__shfl((int)w0h, idxB); H.u[3] = (unsigned)__shfl((int)w1h, idxB);
    L.u[0] = (unsigned)__shfl((int)w0l, idxA); L.u[1] = (unsigned)__shfl((int)w1l, idxA);
    L.u[2] = (unsigned)__shfl((int)w0l, idxB); L.u[3] = (unsigned)__shfl((int)w1l, idxB);
    if (augment && g == 2) { H.u[0] = 0x3F80u; L.u[0] = 0u; }   // k=16 bias row = 1.0
    Bh = H.v; Bl = L.v;
}

__device__ __forceinline__ s16x8 make_B_hi(const float x[4], int idxA, int idxB)
{
    unsigned w0 = cvt_pk_bf16(x[0], x[1]);
    unsigned w1 = cvt_pk_bf16(x[2], x[3]);
    union { unsigned u[4]; s16x8 v; } H;
    H.u[0] = (unsigned)__shfl((int)w0, idxA); H.u[1] = (unsigned)__shfl((int)w1, idxA);
    H.u[2] = (unsigned)__shfl((int)w0, idxB); H.u[3] = (unsigned)__shfl((int)w1, idxB);
    return H.v;
}

// ---------------- pair kernel: 2 tiles (32 pairs) per wave iteration
// pi1 packing: tile t, A-row rr -> ch = 4*(rr>>2)+(t&3), bp = 4*(t>>2)+(rr&3)
__global__ __launch_bounds__(256, 8) void k_pair_mfma(
    const int*   __restrict__ ind2,
    const float* __restrict__ basis,
    const float* __restrict__ ytop,
    const float* __restrict__ ybot,
    const float* __restrict__ Wpi1, const float* __restrict__ bpi1,
    const float* __restrict__ Wii0, const float* __restrict__ Wii1,
    float* __restrict__ i_pair_out,
    const unsigned* __restrict__ starts,
    const unsigned* __restrict__ rank,
    unsigned* __restrict__ sidx)
{
    __shared__ s16x8 a2_lds[12][4][16];   // [t][g][r]

    const int lane = threadIdx.x & 63;
    const int w    = threadIdx.x >> 6;
    const int r    = lane & 15;
    const int g    = lane >> 4;
    const int idxA = (r + 32*g) & 63;
    const int idxB = (idxA + 16) & 63;

    for (int e = threadIdx.x; e < 768; e += 256) {
        int t  = e >> 6;
        int rr = (e >> 2) & 15;
        int gg = e & 3;
        int ch = 4*(rr >> 2) + (t & 3);
        int bp = 4*(t >> 2) + (rr & 3);
        s16x8 val;
#pragma unroll
        for (int j = 0; j < 8; ++j) {
            int k = 8*gg + j;
            float wv = 0.0f;
            if (bp < N_BASIS) {
                if (k < W)       wv = Wpi1[k*(W*N_BASIS) + ch*N_BASIS + bp];
                else if (k == W) wv = bpi1[ch*N_BASIS + bp];
            }
            val[j] = (short)bf16r(SC * wv);
        }
        a2_lds[t][gg][rr] = val;
    }

    s16x8 a3, a4;
#pragma unroll
    for (int j = 0; j < 8; ++j) {
        int k = 8*g + j;
        a3[j] = (short)(k < W ? bf16r(SC * Wii0[k*W + r]) : 0);
        a4[j] = (short)(k < W ? bf16r(SC * Wii1[k*W + r]) : 0);
    }

    __syncthreads();

    for (int sup = blockIdx.x * 4 + w; sup < NSUP; sup += gridDim.x * 4) {
        const int pA = sup * 32 + r;
        const int pB = pA + 16;
        int2 ijA = reinterpret_cast<const int2*>(ind2)[pA];
        int2 ijB = reinterpret_cast<const int2*>(ind2)[pB];

        const f32x4 ytA = *reinterpret_cast<const f32x4*>(ytop + (size_t)ijA.x * W + 4*g);
        const f32x4 ybA = *reinterpret_cast<const f32x4*>(ybot + (size_t)ijA.y * W + 4*g);
        const f32x4 ytB = *reinterpret_cast<const f32x4*>(ytop + (size_t)ijB.x * W + 4*g);
        const f32x4 ybB = *reinterpret_cast<const f32x4*>(ybot + (size_t)ijB.y * W + 4*g);

        float basA[N_BASIS], basB[N_BASIS];
        {
            const float2* bbA = reinterpret_cast<const float2*>(basis + (size_t)pA * N_BASIS);
            const float2* bbB = reinterpret_cast<const float2*>(basis + (size_t)pB * N_BASIS);
#pragma unroll
            for (int q = 0; q < 5; ++q) {
                float2 tA = bbA[q]; basA[2*q] = tA.x; basA[2*q+1] = tA.y;
                float2 tB = bbB[q]; basB[2*q] = tB.x; basB[2*q+1] = tB.y;
            }
        }

        // pi0 (exact, precomputed halves) + tanh
        float h0A[4], h0B[4];
#pragma unroll
        for (int i = 0; i < 4; ++i) {
            h0A[i] = tanh_pre(ytA[i] + ybA[i]);
            h0B[i] = tanh_pre(ytB[i] + ybB[i]);
        }

        s16x8 B2hA, B2lA, B2hB, B2lB;
        make_B_hilo(h0A, idxA, idxB, g, true, B2hA, B2lA);
        make_B_hilo(h0B, idxA, idxB, g, true, B2hB, B2lB);

        // pi1: 12 tiles, in-register basis contraction (skip bp>=10 pads)
        float vlA[4] = {0.f,0.f,0.f,0.f}, vlB[4] = {0.f,0.f,0.f,0.f};
#pragma unroll
        for (int t = 0; t < 12; ++t) {
            s16x8 af = a2_lds[t][g][r];
            f32x4 zA = {0.f,0.f,0.f,0.f}, zB = {0.f,0.f,0.f,0.f};
            zA = __builtin_amdgcn_mfma_f32_16x16x32_bf16(af, B2hA, zA, 0, 0, 0);
            zB = __builtin_amdgcn_mfma_f32_16x16x32_bf16(af, B2hB, zB, 0, 0, 0);
            zA = __builtin_amdgcn_mfma_f32_16x16x32_bf16(af, B2lA, zA, 0, 0, 0);
            zB = __builtin_amdgcn_mfma_f32_16x16x32_bf16(af, B2lB, zB, 0, 0, 0);
#pragma unroll
            for (int i = 0; i < 4; ++i) {
                const int bi = 4*(t >> 2) + i;
                if (bi < N_BASIS) {
                    const int m = t & 3;
                    vlA[m] += tanh_pre(zA[i]) * basA[bi];
                    vlB[m] += tanh_pre(zB[i]) * basB[bi];
                }
            }
        }

        // ii0
        s16x8 B3hA = make_B_hi(vlA, idxA, idxB);
        s16x8 B3hB = make_B_hi(vlB, idxA, idxB);
        f32x4 uaA = {0.f,0.f,0.f,0.f}, uaB = {0.f,0.f,0.f,0.f};
        uaA = __builtin_amdgcn_mfma_f32_16x16x32_bf16(a3, B3hA, uaA, 0, 0, 0);
        uaB = __builtin_amdgcn_mfma_f32_16x16x32_bf16(a3, B3hB, uaB, 0, 0, 0);
        float tuA[4], tuB[4];
#pragma unroll
        for (int i = 0; i < 4; ++i) {
            tuA[i] = tanh_pre(uaA[i]);
            tuB[i] = tanh_pre(uaB[i]);
        }

        // ii1
        s16x8 B4hA = make_B_hi(tuA, idxA, idxB);
        s16x8 B4hB = make_B_hi(tuB, idxA, idxB);
        f32x4 waA = {0.f,0.f,0.f,0.f}, waB = {0.f,0.f,0.f,0.f};
        waA = __builtin_amdgcn_mfma_f32_16x16x32_bf16(a4, B4hA, waA, 0, 0, 0);
        waB = __builtin_amdgcn_mfma_f32_16x16x32_bf16(a4, B4hB, waB, 0, 0, 0);
        float4 outA = make_float4(tanh_pre(waA[0]), tanh_pre(waA[1]),
                                  tanh_pre(waA[2]), tanh_pre(waA[3]));
        float4 outB = make_float4(tanh_pre(waB[0]), tanh_pre(waB[1]),
                                  tanh_pre(waB[2]), tanh_pre(waB[3]));

        *reinterpret_cast<float4*>(i_pair_out + (size_t)pA * W + 4*g) = outA;
        *reinterpret_cast<float4*>(i_pair_out + (size_t)pB * W + 4*g) = outB;

        if (g == 0) {
            sidx[starts[ijA.x] + rank[pA]] = (unsigned)pA;
            sidx[starts[ijB.x] + rank[pB]] = (unsigned)pB;
        }
    }
}

// ---------------- IP pipeline
__global__ __launch_bounds__(256) void k_count(const int* __restrict__ ind2,
                                               unsigned* __restrict__ counts,
                                               unsigned* __restrict__ rank)
{
    int p = blockIdx.x * 256 + threadIdx.x;
    if (p >= N_PAIRS) return;
    rank[p] = atomicAdd(&counts[ind2[2*p]], 1u);
}

__global__ __launch_bounds__(SCAN_BLK) void k_scanA(const unsigned* __restrict__ counts,
                                                    unsigned* __restrict__ starts,
                                                    unsigned* __restrict__ bsum)
{
    __shared__ unsigned sc[SCAN_BLK];
    int a = blockIdx.x * SCAN_BLK + threadIdx.x;
    unsigned c = (a < N_ATOMS) ? counts[a] : 0u;
    sc[threadIdx.x] = c;
    __syncthreads();
    for (int off = 1; off < SCAN_BLK; off <<= 1) {
        unsigned v = sc[threadIdx.x];
        unsigned add = (threadIdx.x >= off) ? sc[threadIdx.x - off] : 0u;
        __syncthreads();
        sc[threadIdx.x] = v + add;
        __syncthreads();
    }
    if (a < N_ATOMS) starts[a] = sc[threadIdx.x] - c;
    if (threadIdx.x == SCAN_BLK - 1) bsum[blockIdx.x] = sc[SCAN_BLK - 1];
}

__global__ __launch_bounds__(128) void k_scanB(const unsigned* __restrict__ bsum,
                                               unsigned* __restrict__ boff)
{
    __shared__ unsigned s[128];
    int t = threadIdx.x;
    unsigned v = (t < NB) ? bsum[t] : 0u;
    s[t] = v;
    __syncthreads();
    for (int off = 1; off < 128; off <<= 1) {
        unsigned x = s[t];
        unsigned add = (t >= off) ? s[t - off] : 0u;
        __syncthreads();
        s[t] = x + add;
        __syncthreads();
    }
    if (t < NB) boff[t] = s[t] - v;
}

__global__ __launch_bounds__(SCAN_BLK) void k_scanC(unsigned* __restrict__ starts,
                                                    const unsigned* __restrict__ boff)
{
    int a = blockIdx.x * SCAN_BLK + threadIdx.x;
    if (a >= N_ATOMS) return;
    starts[a] += boff[blockIdx.x];
}

// gather-reduce: i_pair is L3-resident (205 MB < 256 MB), random reads mostly skip HBM
__global__ __launch_bounds__(256) void k_reduce_gather(const unsigned* __restrict__ starts,
                                                       const unsigned* __restrict__ counts,
                                                       const unsigned* __restrict__ sidx,
                                                       const float* __restrict__ i_pair,
                                                       float* __restrict__ p_sum)
{
    int a = blockIdx.x * 4 + (threadIdx.x >> 6);
    if (a >= N_ATOMS) return;
    int lane = threadIdx.x & 63;
    int c = lane & 15, q = lane >> 4;
    unsigned n = counts[a], st = starts[a];
    float acc = 0.0f;
    for (unsigned k = q; k < n; k += 4) {
        unsigned pid = sidx[st + k];
        acc += i_pair[(size_t)pid * W + c];
    }
    acc += __shfl_xor(acc, 16);
    acc += __shfl_xor(acc, 32);
    if (q == 0) p_sum[(size_t)a * W + c] = acc;
}

// ---------------- pp_post
__global__ __launch_bounds__(256) void k_pp_post(
    const float* __restrict__ p_sum,
    const float* __restrict__ W0, const float* __restrict__ W1,
    float* __restrict__ p1_new)
{
    int a = blockIdx.x * 256 + threadIdx.x;
    if (a >= N_ATOMS) return;
    const float4* src = reinterpret_cast<const float4*>(p_sum + (size_t)a * W);
    float4 v0 = src[0], v1 = src[1], v2 = src[2], v3 = src[3];
    float x[W] = {v0.x,v0.y,v0.z,v0.w, v1.x,v1.y,v1.z,v1.w,
                  v2.x,v2.y,v2.z,v2.w, v3.x,v3.y,v3.z,v3.w};
    float h[W];
#pragma unroll
    for (int c = 0; c < W; ++c) h[c] = 0.0f;
#pragma unroll
    for (int k = 0; k < W; ++k)
#pragma unroll
        for (int c = 0; c < W; ++c) h[c] += x[k] * W0[k*W + c];
#pragma unroll
    for (int c = 0; c < W; ++c) h[c] = fast_tanh(h[c]);
    float y[W];
#pragma unroll
    for (int c = 0; c < W; ++c) y[c] = 0.0f;
#pragma unroll
    for (int k = 0; k < W; ++k)
#pragma unroll
        for (int c = 0; c < W; ++c) y[c] += h[k] * W1[k*W + c];
    float4* dst = reinterpret_cast<float4*>(p1_new + (size_t)a * W);
    dst[0] = make_float4(fast_tanh(y[0]),  fast_tanh(y[1]),  fast_tanh(y[2]),  fast_tanh(y[3]));
    dst[1] = make_float4(fast_tanh(y[4]),  fast_tanh(y[5]),  fast_tanh(y[6]),  fast_tanh(y[7]));
    dst[2] = make_float4(fast_tanh(y[8]),  fast_tanh(y[9]),  fast_tanh(y[10]), fast_tanh(y[11]));
    dst[3] = make_float4(fast_tanh(y[12]), fast_tanh(y[13]), fast_tanh(y[14]), fast_tanh(y[15]));
}

extern "C" void kernel_launch(void* const* d_in, const int* in_sizes, int n_in,
                              void* d_out, int out_size, void* d_ws, size_t ws_size,
                              hipStream_t stream) {
    const int*   ind2   = (const int*)d_in[0];
    const float* p1     = (const float*)d_in[1];
    const float* basis  = (const float*)d_in[2];
    const float* Wpre0  = (const float*)d_in[3];
    const float* bpre0  = (const float*)d_in[4];
    const float* Wpre1  = (const float*)d_in[5];
    const float* bpre1  = (const float*)d_in[6];
    const float* Wpi0   = (const float*)d_in[7];
    const float* bpi0   = (const float*)d_in[8];
    const float* Wpi1   = (const float*)d_in[9];
    const float* bpi1   = (const float*)d_in[10];
    const float* Wii0   = (const float*)d_in[11];
    const float* Wii1   = (const float*)d_in[12];
    const float* Wpost0 = (const float*)d_in[13];
    const float* Wpost1 = (const float*)d_in[14];

    float* out    = (float*)d_out;
    float* p1_new = out;                          // (N_ATOMS, W)
    float* i_pair = out + (size_t)N_ATOMS * W;    // (N_PAIRS, W)

    char* ws = (char*)d_ws;
    float*    ytop   = (float*)ws;                                ws += (size_t)N_ATOMS * W * 4;
    float*    ybot   = (float*)ws;                                ws += (size_t)N_ATOMS * W * 4;
    float*    p_sum  = (float*)ws;                                ws += (size_t)N_ATOMS * W * 4;
    unsigned* counts = (unsigned*)ws;                             ws += (size_t)N_ATOMS * 4;
    unsigned* starts = (unsigned*)ws;                             ws += (size_t)N_ATOMS * 4;
    unsigned* bsum   = (unsigned*)ws;                             ws += 1024 * 4;
    unsigned* boff   = (unsigned*)ws;                             ws += 1024 * 4;
    unsigned* rank   = (unsigned*)ws;                             ws += (size_t)N_PAIRS * 4;
    unsigned* sidx   = (unsigned*)ws;                             ws += (size_t)N_PAIRS * 4;

    hipMemsetAsync(counts, 0, (size_t)N_ATOMS * sizeof(unsigned), stream);
    k_pp_pre<<<(N_ATOMS + 255) / 256, 256, 0, stream>>>(p1, Wpre0, bpre0, Wpre1, bpre1,
                                                        Wpi0, bpi0, ytop, ybot);
    k_count<<<(N_PAIRS + 255) / 256, 256, 0, stream>>>(ind2, counts, rank);
    k_scanA<<<NB, SCAN_BLK, 0, stream>>>(counts, starts, bsum);
    k_scanB<<<1, 128, 0, stream>>>(bsum, boff);
    k_scanC<<<NB, SCAN_BLK, 0, stream>>>(starts, boff);

    k_pair_mfma<<<2048, 256, 0, stream>>>(ind2, basis, ytop, ybot,
                                          Wpi1, bpi1, Wii0, Wii1,
                                          i_pair, starts, rank, sidx);
    k_reduce_gather<<<(N_ATOMS + 3) / 4, 256, 0, stream>>>(starts, counts, sidx, i_pair, p_sum);
    k_pp_post<<<(N_ATOMS + 255) / 256, 256, 0, stream>>>(p_sum, Wpost0, Wpost1, p1_new);
}

// Round 7
// 559.001 us; speedup vs baseline: 1.3155x; 1.3155x over previous
//
#include <hip/hip_runtime.h>

#define N_ATOMS 100000
#define N_PAIRS 3200000
#define N_PROP 16
#define N_BASIS 10
#define W 16
#define NSUP (N_PAIRS / 32)   // 100000 2-tile supers (32 pairs each)
#define SCAN_BLK 1024
#define NB ((N_ATOMS + SCAN_BLK - 1) / SCAN_BLK)   // 98
#define SC 2.88539008177792681f   // 2*log2(e), folded into weights/pre-acts

typedef short  s16x8 __attribute__((ext_vector_type(8)));
typedef float  f32x4 __attribute__((ext_vector_type(4)));

__device__ __forceinline__ float tanh_pre(float y) {   // y = SC*x
    float e = __builtin_amdgcn_exp2f(y);
    return 1.0f - 2.0f * __builtin_amdgcn_rcpf(e + 1.0f);
}
__device__ __forceinline__ float fast_tanh(float x) {
    float e = __builtin_amdgcn_exp2f(x * SC);
    return 1.0f - 2.0f * __builtin_amdgcn_rcpf(e + 1.0f);
}
__device__ __forceinline__ unsigned short bf16r(float f) {
    union { float f; unsigned u; } v; v.f = f;
    unsigned r = v.u + 0x7FFFu + ((v.u >> 16) & 1u);
    return (unsigned short)(r >> 16);
}
__device__ __forceinline__ unsigned cvt_pk_bf16(float a, float b) {
    unsigned r;
    asm("v_cvt_pk_bf16_f32 %0, %1, %2" : "=v"(r) : "v"(a), "v"(b));
    return r;
}
__device__ __forceinline__ float bitf(unsigned u) {
    union { unsigned u; float f; } v; v.u = u; return v.f;
}

// ---------------- pp_pre: p1_in + fused pi0 per-atom halves (f32, SC+bias folded)
__global__ __launch_bounds__(256) void k_pp_pre(
    const float* __restrict__ p1,
    const float* __restrict__ W0, const float* __restrict__ b0,
    const float* __restrict__ W1, const float* __restrict__ b1,
    const float* __restrict__ Wpi0, const float* __restrict__ bpi0,
    float* __restrict__ ytop, float* __restrict__ ybot)
{
    int a = blockIdx.x * 256 + threadIdx.x;
    if (a >= N_ATOMS) return;
    const float4* src = reinterpret_cast<const float4*>(p1 + (size_t)a * N_PROP);
    float4 v0 = src[0], v1 = src[1], v2 = src[2], v3 = src[3];
    float x[N_PROP] = {v0.x,v0.y,v0.z,v0.w, v1.x,v1.y,v1.z,v1.w,
                       v2.x,v2.y,v2.z,v2.w, v3.x,v3.y,v3.z,v3.w};
    float h[W];
#pragma unroll
    for (int c = 0; c < W; ++c) h[c] = b0[c];
#pragma unroll
    for (int k = 0; k < N_PROP; ++k)
#pragma unroll
        for (int c = 0; c < W; ++c) h[c] += x[k] * W0[k*W + c];
#pragma unroll
    for (int c = 0; c < W; ++c) h[c] = fast_tanh(h[c]);
    float y[W];
#pragma unroll
    for (int c = 0; c < W; ++c) y[c] = b1[c];
#pragma unroll
    for (int k = 0; k < W; ++k)
#pragma unroll
        for (int c = 0; c < W; ++c) y[c] += h[k] * W1[k*W + c];
    float t[W];
#pragma unroll
    for (int c = 0; c < W; ++c) t[c] = fast_tanh(y[c]);

    float yt[W], yb[W];
#pragma unroll
    for (int c = 0; c < W; ++c) { yt[c] = bpi0[c]; yb[c] = 0.0f; }
#pragma unroll
    for (int k = 0; k < W; ++k)
#pragma unroll
        for (int c = 0; c < W; ++c) {
            yt[c] += t[k] * Wpi0[k*W + c];
            yb[c] += t[k] * Wpi0[(W + k)*W + c];
        }
    float4* dt = reinterpret_cast<float4*>(ytop + (size_t)a * W);
    float4* db = reinterpret_cast<float4*>(ybot + (size_t)a * W);
#pragma unroll
    for (int q = 0; q < 4; ++q) {
        dt[q] = make_float4(SC*yt[4*q], SC*yt[4*q+1], SC*yt[4*q+2], SC*yt[4*q+3]);
        db[q] = make_float4(SC*yb[4*q], SC*yb[4*q+1], SC*yb[4*q+2], SC*yb[4*q+3]);
    }
}

// C-layout x[i] (ch 4g+i, pair r) -> B-frag (k=8g'+j), hi/lo split
__device__ __forceinline__ void make_B_hilo(const float x[4], int idxA, int idxB,
                                            int g, bool augment, s16x8& Bh, s16x8& Bl)
{
    unsigned w0h = cvt_pk_bf16(x[0], x[1]);
    unsigned w1h = cvt_pk_bf16(x[2], x[3]);
    float f0 = bitf(w0h << 16), f1 = bitf(w0h & 0xFFFF0000u);
    float f2 = bitf(w1h << 16), f3 = bitf(w1h & 0xFFFF0000u);
    unsigned w0l = cvt_pk_bf16(x[0] - f0, x[1] - f1);
    unsigned w1l = cvt_pk_bf16(x[2] - f2, x[3] - f3);
    union { unsigned u[4]; s16x8 v; } H, L;
    H.u[0] = (unsigned)__shfl((int)w0h, idxA); H.u[1] = (unsigned)__shfl((int)w1h, idxA);
    H.u[2] = (unsigned)__shfl((int)w0h, idxB); H.u[3] = (unsigned)__shfl((int)w1h, idxB);
    L.u[0] = (unsigned)__shfl((int)w0l, idxA); L.u[1] = (unsigned)__shfl((int)w1l, idxA);
    L.u[2] = (unsigned)__shfl((int)w0l, idxB); L.u[3] = (unsigned)__shfl((int)w1l, idxB);
    if (augment && g == 2) { H.u[0] = 0x3F80u; L.u[0] = 0u; }   // k=16 bias row = 1.0
    Bh = H.v; Bl = L.v;
}

__device__ __forceinline__ s16x8 make_B_hi(const float x[4], int idxA, int idxB)
{
    unsigned w0 = cvt_pk_bf16(x[0], x[1]);
    unsigned w1 = cvt_pk_bf16(x[2], x[3]);
    union { unsigned u[4]; s16x8 v; } H;
    H.u[0] = (unsigned)__shfl((int)w0, idxA); H.u[1] = (unsigned)__shfl((int)w1, idxA);
    H.u[2] = (unsigned)__shfl((int)w0, idxB); H.u[3] = (unsigned)__shfl((int)w1, idxB);
    return H.v;
}

// ---------------- pair kernel: 2 tiles/iter, 1-deep software pipeline
template<int USE_RANK>
__global__ __launch_bounds__(256) void k_pair_mfma(
    const int*   __restrict__ ind2,
    const float* __restrict__ basis,
    const float* __restrict__ ytop,
    const float* __restrict__ ybot,
    const float* __restrict__ Wpi1, const float* __restrict__ bpi1,
    const float* __restrict__ Wii0, const float* __restrict__ Wii1,
    float* __restrict__ i_pair_out,
    const unsigned* __restrict__ starts,
    const unsigned* __restrict__ rank,
    unsigned* __restrict__ cursor,
    float* __restrict__ svals)
{
    __shared__ s16x8 a2_lds[12][4][16];   // [t][g][r]

    const int lane = threadIdx.x & 63;
    const int w    = threadIdx.x >> 6;
    const int r    = lane & 15;
    const int g    = lane >> 4;
    const int idxA = (r + 32*g) & 63;
    const int idxB = (idxA + 16) & 63;
    const int2* ind2v = reinterpret_cast<const int2*>(ind2);

    for (int e = threadIdx.x; e < 768; e += 256) {
        int t  = e >> 6;
        int rr = (e >> 2) & 15;
        int gg = e & 3;
        int ch = 4*(rr >> 2) + (t & 3);
        int bp = 4*(t >> 2) + (rr & 3);
        s16x8 val;
#pragma unroll
        for (int j = 0; j < 8; ++j) {
            int k = 8*gg + j;
            float wv = 0.0f;
            if (bp < N_BASIS) {
                if (k < W)       wv = Wpi1[k*(W*N_BASIS) + ch*N_BASIS + bp];
                else if (k == W) wv = bpi1[ch*N_BASIS + bp];
            }
            val[j] = (short)bf16r(SC * wv);
        }
        a2_lds[t][gg][rr] = val;
    }

    s16x8 a3, a4;
#pragma unroll
    for (int j = 0; j < 8; ++j) {
        int k = 8*g + j;
        a3[j] = (short)(k < W ? bf16r(SC * Wii0[k*W + r]) : 0);
        a4[j] = (short)(k < W ? bf16r(SC * Wii1[k*W + r]) : 0);
    }

    __syncthreads();

    const int stride = gridDim.x * 4;
    int sup = blockIdx.x * 4 + w;
    if (sup >= NSUP) return;

    // prologue: load state for first iteration
    int2 ijA = ind2v[(size_t)sup * 32 + r];
    int2 ijB = ind2v[(size_t)sup * 32 + r + 16];
    f32x4 ytA = *reinterpret_cast<const f32x4*>(ytop + (size_t)ijA.x * W + 4*g);
    f32x4 ybA = *reinterpret_cast<const f32x4*>(ybot + (size_t)ijA.y * W + 4*g);
    f32x4 ytB = *reinterpret_cast<const f32x4*>(ytop + (size_t)ijB.x * W + 4*g);
    f32x4 ybB = *reinterpret_cast<const f32x4*>(ybot + (size_t)ijB.y * W + 4*g);

    for (; sup < NSUP; sup += stride) {
        const int pA = sup * 32 + r;
        const int pB = pA + 16;
        const int nsupc = (sup + stride < NSUP) ? (sup + stride) : sup;

        // (1) issue next ind2 loads — latency hidden under pi0+pi1
        int2 nijA = ind2v[(size_t)nsupc * 32 + r];
        int2 nijB = ind2v[(size_t)nsupc * 32 + r + 16];

        // (2) pi0 (precomputed halves) + tanh
        float h0A[4], h0B[4];
#pragma unroll
        for (int i = 0; i < 4; ++i) {
            h0A[i] = tanh_pre(ytA[i] + ybA[i]);
            h0B[i] = tanh_pre(ytB[i] + ybB[i]);
        }
        s16x8 B2hA, B2lA, B2hB, B2lB;
        make_B_hilo(h0A, idxA, idxB, g, true, B2hA, B2lA);
        make_B_hilo(h0B, idxA, idxB, g, true, B2hB, B2lB);

        // (3) basis for current (streamed, short issue-to-use distance ok)
        float basA[N_BASIS], basB[N_BASIS];
        {
            const float2* bbA = reinterpret_cast<const float2*>(basis + (size_t)pA * N_BASIS);
            const float2* bbB = reinterpret_cast<const float2*>(basis + (size_t)pB * N_BASIS);
#pragma unroll
            for (int q = 0; q < 5; ++q) {
                float2 tA = bbA[q]; basA[2*q] = tA.x; basA[2*q+1] = tA.y;
                float2 tB = bbB[q]; basB[2*q] = tB.x; basB[2*q+1] = tB.y;
            }
        }

        // (4) pi1: 12 tiles, in-register basis contraction
        float vlA[4] = {0.f,0.f,0.f,0.f}, vlB[4] = {0.f,0.f,0.f,0.f};
#pragma unroll
        for (int t = 0; t < 12; ++t) {
            s16x8 af = a2_lds[t][g][r];
            f32x4 zA = {0.f,0.f,0.f,0.f}, zB = {0.f,0.f,0.f,0.f};
            zA = __builtin_amdgcn_mfma_f32_16x16x32_bf16(af, B2hA, zA, 0, 0, 0);
            zB = __builtin_amdgcn_mfma_f32_16x16x32_bf16(af, B2hB, zB, 0, 0, 0);
            zA = __builtin_amdgcn_mfma_f32_16x16x32_bf16(af, B2lA, zA, 0, 0, 0);
            zB = __builtin_amdgcn_mfma_f32_16x16x32_bf16(af, B2lB, zB, 0, 0, 0);
#pragma unroll
            for (int i = 0; i < 4; ++i) {
                const int bi = 4*(t >> 2) + i;
                if (bi < N_BASIS) {
                    const int m = t & 3;
                    vlA[m] += tanh_pre(zA[i]) * basA[bi];
                    vlB[m] += tanh_pre(zB[i]) * basB[bi];
                }
            }
        }

        // (5) issue next gathers — nij* has landed by now
        f32x4 nytA = *reinterpret_cast<const f32x4*>(ytop + (size_t)nijA.x * W + 4*g);
        f32x4 nybA = *reinterpret_cast<const f32x4*>(ybot + (size_t)nijA.y * W + 4*g);
        f32x4 nytB = *reinterpret_cast<const f32x4*>(ytop + (size_t)nijB.x * W + 4*g);
        f32x4 nybB = *reinterpret_cast<const f32x4*>(ybot + (size_t)nijB.y * W + 4*g);

        // (6) ii0
        s16x8 B3hA = make_B_hi(vlA, idxA, idxB);
        s16x8 B3hB = make_B_hi(vlB, idxA, idxB);
        f32x4 uaA = {0.f,0.f,0.f,0.f}, uaB = {0.f,0.f,0.f,0.f};
        uaA = __builtin_amdgcn_mfma_f32_16x16x32_bf16(a3, B3hA, uaA, 0, 0, 0);
        uaB = __builtin_amdgcn_mfma_f32_16x16x32_bf16(a3, B3hB, uaB, 0, 0, 0);
        float tuA[4], tuB[4];
#pragma unroll
        for (int i = 0; i < 4; ++i) {
            tuA[i] = tanh_pre(uaA[i]);
            tuB[i] = tanh_pre(uaB[i]);
        }

        // (7) ii1
        s16x8 B4hA = make_B_hi(tuA, idxA, idxB);
        s16x8 B4hB = make_B_hi(tuB, idxA, idxB);
        f32x4 waA = {0.f,0.f,0.f,0.f}, waB = {0.f,0.f,0.f,0.f};
        waA = __builtin_amdgcn_mfma_f32_16x16x32_bf16(a4, B4hA, waA, 0, 0, 0);
        waB = __builtin_amdgcn_mfma_f32_16x16x32_bf16(a4, B4hB, waB, 0, 0, 0);
        float4 outA = make_float4(tanh_pre(waA[0]), tanh_pre(waA[1]),
                                  tanh_pre(waA[2]), tanh_pre(waA[3]));
        float4 outB = make_float4(tanh_pre(waB[0]), tanh_pre(waB[1]),
                                  tanh_pre(waB[2]), tanh_pre(waB[3]));

        *reinterpret_cast<float4*>(i_pair_out + (size_t)pA * W + 4*g) = outA;
        *reinterpret_cast<float4*>(i_pair_out + (size_t)pB * W + 4*g) = outB;

        unsigned posA, posB;
        if (USE_RANK) {
            posA = starts[ijA.x] + rank[pA];
            posB = starts[ijB.x] + rank[pB];
        } else {
            unsigned ppA = 0, ppB = 0;
            if (g == 0) {
                ppA = atomicAdd(&cursor[ijA.x], 1u);
                ppB = atomicAdd(&cursor[ijB.x], 1u);
            }
            posA = (unsigned)__shfl((int)ppA, r);
            posB = (unsigned)__shfl((int)ppB, r);
        }
        *reinterpret_cast<float4*>(svals + (size_t)posA * W + 4*g) = outA;
        *reinterpret_cast<float4*>(svals + (size_t)posB * W + 4*g) = outB;

        // (8) rotate pipeline state
        ijA = nijA; ijB = nijB;
        ytA = nytA; ybA = nybA; ytB = nytB; ybB = nybB;
    }
}

// ---------------- IP pipeline
__global__ __launch_bounds__(256) void k_count(const int* __restrict__ ind2,
                                               unsigned* __restrict__ counts,
                                               unsigned* __restrict__ rank)
{
    int p = blockIdx.x * 256 + threadIdx.x;
    if (p >= N_PAIRS) return;
    rank[p] = atomicAdd(&counts[ind2[2*p]], 1u);
}

__global__ __launch_bounds__(SCAN_BLK) void k_scanA(const unsigned* __restrict__ counts,
                                                    unsigned* __restrict__ starts,
                                                    unsigned* __restrict__ bsum)
{
    __shared__ unsigned sc[SCAN_BLK];
    int a = blockIdx.x * SCAN_BLK + threadIdx.x;
    unsigned c = (a < N_ATOMS) ? counts[a] : 0u;
    sc[threadIdx.x] = c;
    __syncthreads();
    for (int off = 1; off < SCAN_BLK; off <<= 1) {
        unsigned v = sc[threadIdx.x];
        unsigned add = (threadIdx.x >= off) ? sc[threadIdx.x - off] : 0u;
        __syncthreads();
        sc[threadIdx.x] = v + add;
        __syncthreads();
    }
    if (a < N_ATOMS) starts[a] = sc[threadIdx.x] - c;
    if (threadIdx.x == SCAN_BLK - 1) bsum[blockIdx.x] = sc[SCAN_BLK - 1];
}

__global__ __launch_bounds__(128) void k_scanB(const unsigned* __restrict__ bsum,
                                               unsigned* __restrict__ boff)
{
    __shared__ unsigned s[128];
    int t = threadIdx.x;
    unsigned v = (t < NB) ? bsum[t] : 0u;
    s[t] = v;
    __syncthreads();
    for (int off = 1; off < 128; off <<= 1) {
        unsigned x = s[t];
        unsigned add = (t >= off) ? s[t - off] : 0u;
        __syncthreads();
        s[t] = x + add;
        __syncthreads();
    }
    if (t < NB) boff[t] = s[t] - v;
}

__global__ __launch_bounds__(SCAN_BLK) void k_scanC(unsigned* __restrict__ starts,
                                                    const unsigned* __restrict__ boff,
                                                    unsigned* __restrict__ cursor)
{
    int a = blockIdx.x * SCAN_BLK + threadIdx.x;
    if (a >= N_ATOMS) return;
    unsigned s = starts[a] + boff[blockIdx.x];
    starts[a] = s;
    cursor[a] = s;
}

__global__ __launch_bounds__(256) void k_reduce_stream(const unsigned* __restrict__ starts,
                                                       const unsigned* __restrict__ counts,
                                                       const float* __restrict__ svals,
                                                       float* __restrict__ p_sum)
{
    int a = blockIdx.x * 4 + (threadIdx.x >> 6);
    if (a >= N_ATOMS) return;
    int lane = threadIdx.x & 63;
    int c = lane & 15, q = lane >> 4;
    unsigned n = counts[a], st = starts[a];
    float acc = 0.0f;
    for (unsigned k = q; k < n; k += 4)
        acc += svals[(size_t)(st + k) * W + c];
    acc += __shfl_xor(acc, 16);
    acc += __shfl_xor(acc, 32);
    if (q == 0) p_sum[(size_t)a * W + c] = acc;
}

// ---------------- pp_post
__global__ __launch_bounds__(256) void k_pp_post(
    const float* __restrict__ p_sum,
    const float* __restrict__ W0, const float* __restrict__ W1,
    float* __restrict__ p1_new)
{
    int a = blockIdx.x * 256 + threadIdx.x;
    if (a >= N_ATOMS) return;
    const float4* src = reinterpret_cast<const float4*>(p_sum + (size_t)a * W);
    float4 v0 = src[0], v1 = src[1], v2 = src[2], v3 = src[3];
    float x[W] = {v0.x,v0.y,v0.z,v0.w, v1.x,v1.y,v1.z,v1.w,
                  v2.x,v2.y,v2.z,v2.w, v3.x,v3.y,v3.z,v3.w};
    float h[W];
#pragma unroll
    for (int c = 0; c < W; ++c) h[c] = 0.0f;
#pragma unroll
    for (int k = 0; k < W; ++k)
#pragma unroll
        for (int c = 0; c < W; ++c) h[c] += x[k] * W0[k*W + c];
#pragma unroll
    for (int c = 0; c < W; ++c) h[c] = fast_tanh(h[c]);
    float y[W];
#pragma unroll
    for (int c = 0; c < W; ++c) y[c] = 0.0f;
#pragma unroll
    for (int k = 0; k < W; ++k)
#pragma unroll
        for (int c = 0; c < W; ++c) y[c] += h[k] * W1[k*W + c];
    float4* dst = reinterpret_cast<float4*>(p1_new + (size_t)a * W);
    dst[0] = make_float4(fast_tanh(y[0]),  fast_tanh(y[1]),  fast_tanh(y[2]),  fast_tanh(y[3]));
    dst[1] = make_float4(fast_tanh(y[4]),  fast_tanh(y[5]),  fast_tanh(y[6]),  fast_tanh(y[7]));
    dst[2] = make_float4(fast_tanh(y[8]),  fast_tanh(y[9]),  fast_tanh(y[10]), fast_tanh(y[11]));
    dst[3] = make_float4(fast_tanh(y[12]), fast_tanh(y[13]), fast_tanh(y[14]), fast_tanh(y[15]));
}

extern "C" void kernel_launch(void* const* d_in, const int* in_sizes, int n_in,
                              void* d_out, int out_size, void* d_ws, size_t ws_size,
                              hipStream_t stream) {
    const int*   ind2   = (const int*)d_in[0];
    const float* p1     = (const float*)d_in[1];
    const float* basis  = (const float*)d_in[2];
    const float* Wpre0  = (const float*)d_in[3];
    const float* bpre0  = (const float*)d_in[4];
    const float* Wpre1  = (const float*)d_in[5];
    const float* bpre1  = (const float*)d_in[6];
    const float* Wpi0   = (const float*)d_in[7];
    const float* bpi0   = (const float*)d_in[8];
    const float* Wpi1   = (const float*)d_in[9];
    const float* bpi1   = (const float*)d_in[10];
    const float* Wii0   = (const float*)d_in[11];
    const float* Wii1   = (const float*)d_in[12];
    const float* Wpost0 = (const float*)d_in[13];
    const float* Wpost1 = (const float*)d_in[14];

    float* out    = (float*)d_out;
    float* p1_new = out;                          // (N_ATOMS, W)
    float* i_pair = out + (size_t)N_ATOMS * W;    // (N_PAIRS, W)

    char* ws = (char*)d_ws;
    float*    ytop   = (float*)ws;                                ws += (size_t)N_ATOMS * W * 4;
    float*    ybot   = (float*)ws;                                ws += (size_t)N_ATOMS * W * 4;
    float*    p_sum  = (float*)ws;                                ws += (size_t)N_ATOMS * W * 4;
    unsigned* counts = (unsigned*)ws;                             ws += (size_t)N_ATOMS * 4;
    unsigned* starts = (unsigned*)ws;                             ws += (size_t)N_ATOMS * 4;
    unsigned* cursor = (unsigned*)ws;                             ws += (size_t)N_ATOMS * 4;
    unsigned* bsum   = (unsigned*)ws;                             ws += 1024 * 4;
    unsigned* boff   = (unsigned*)ws;                             ws += 1024 * 4;
    float*    svals  = (float*)ws;                                ws += (size_t)N_PAIRS * W * 4;
    unsigned* rank   = (unsigned*)ws;                             ws += (size_t)N_PAIRS * 4;

    int use_rank = (ws_size >= (size_t)(ws - (char*)d_ws));

    hipMemsetAsync(counts, 0, (size_t)N_ATOMS * sizeof(unsigned), stream);
    k_pp_pre<<<(N_ATOMS + 255) / 256, 256, 0, stream>>>(p1, Wpre0, bpre0, Wpre1, bpre1,
                                                        Wpi0, bpi0, ytop, ybot);
    k_count<<<(N_PAIRS + 255) / 256, 256, 0, stream>>>(ind2, counts, use_rank ? rank : cursor);
    k_scanA<<<NB, SCAN_BLK, 0, stream>>>(counts, starts, bsum);
    k_scanB<<<1, 128, 0, stream>>>(bsum, boff);
    k_scanC<<<NB, SCAN_BLK, 0, stream>>>(starts, boff, cursor);

    if (use_rank) {
        k_pair_mfma<1><<<2560, 256, 0, stream>>>(ind2, basis, ytop, ybot,
                                                 Wpi1, bpi1, Wii0, Wii1,
                                                 i_pair, starts, rank, cursor, svals);
    } else {
        k_pair_mfma<0><<<2560, 256, 0, stream>>>(ind2, basis, ytop, ybot,
                                                 Wpi1, bpi1, Wii0, Wii1,
                                                 i_pair, starts, rank, cursor, svals);
    }
    k_reduce_stream<<<(N_ATOMS + 3) / 4, 256, 0, stream>>>(starts, counts, svals, p_sum);
    k_pp_post<<<(N_ATOMS + 255) / 256, 256, 0, stream>>>(p_sum, Wpost0, Wpost1, p1_new);
}

// Round 9
// 548.436 us; speedup vs baseline: 1.3409x; 1.0193x over previous
//
#include <hip/hip_runtime.h>

#define N_ATOMS 100000
#define N_PAIRS 3200000
#define N_PROP 16
#define N_BASIS 10
#define W 16
#define NSUP (N_PAIRS / 32)   // 100000 supers, 32 pairs each
#define SCAN_BLK 1024
#define NB ((N_ATOMS + SCAN_BLK - 1) / SCAN_BLK)   // 98
#define SC 2.88539008177792681f   // 2*log2(e), folded into weights/pre-acts

typedef short  s16x8  __attribute__((ext_vector_type(8)));
typedef float  f32x4  __attribute__((ext_vector_type(4)));
typedef float  f32x16 __attribute__((ext_vector_type(16)));

__device__ __forceinline__ float tanh_pre(float y) {   // y = SC*x
    float e = __builtin_amdgcn_exp2f(y);
    return 1.0f - 2.0f * __builtin_amdgcn_rcpf(e + 1.0f);
}
__device__ __forceinline__ float fast_tanh(float x) {
    float e = __builtin_amdgcn_exp2f(x * SC);
    return 1.0f - 2.0f * __builtin_amdgcn_rcpf(e + 1.0f);
}
__device__ __forceinline__ unsigned short bf16r(float f) {
    union { float f; unsigned u; } v; v.f = f;
    unsigned r = v.u + 0x7FFFu + ((v.u >> 16) & 1u);
    return (unsigned short)(r >> 16);
}
__device__ __forceinline__ unsigned cvt_pk_bf16(float a, float b) {
    unsigned r;
    asm("v_cvt_pk_bf16_f32 %0, %1, %2" : "=v"(r) : "v"(a), "v"(b));
    return r;   // low16 = bf16(a), high16 = bf16(b), RTNE
}
__device__ __forceinline__ float bitf(unsigned u) {
    union { unsigned u; float f; } v; v.u = u; return v.f;
}
__device__ __forceinline__ void nt_store4(float* p, float a, float b, float c, float d) {
    f32x4 v = {a, b, c, d};
    __builtin_nontemporal_store(v, reinterpret_cast<f32x4*>(p));
}

// ---------------- pp_pre: fused pi0 per-atom halves (f32, SC+bias folded)
__global__ __launch_bounds__(256) void k_pp_pre(
    const float* __restrict__ p1,
    const float* __restrict__ W0, const float* __restrict__ b0,
    const float* __restrict__ W1, const float* __restrict__ b1,
    const float* __restrict__ Wpi0, const float* __restrict__ bpi0,
    float* __restrict__ ytop, float* __restrict__ ybot)
{
    int a = blockIdx.x * 256 + threadIdx.x;
    if (a >= N_ATOMS) return;
    const float4* src = reinterpret_cast<const float4*>(p1 + (size_t)a * N_PROP);
    float4 v0 = src[0], v1 = src[1], v2 = src[2], v3 = src[3];
    float x[N_PROP] = {v0.x,v0.y,v0.z,v0.w, v1.x,v1.y,v1.z,v1.w,
                       v2.x,v2.y,v2.z,v2.w, v3.x,v3.y,v3.z,v3.w};
    float h[W];
#pragma unroll
    for (int c = 0; c < W; ++c) h[c] = b0[c];
#pragma unroll
    for (int k = 0; k < N_PROP; ++k)
#pragma unroll
        for (int c = 0; c < W; ++c) h[c] += x[k] * W0[k*W + c];
#pragma unroll
    for (int c = 0; c < W; ++c) h[c] = fast_tanh(h[c]);
    float y[W];
#pragma unroll
    for (int c = 0; c < W; ++c) y[c] = b1[c];
#pragma unroll
    for (int k = 0; k < W; ++k)
#pragma unroll
        for (int c = 0; c < W; ++c) y[c] += h[k] * W1[k*W + c];
    float t[W];
#pragma unroll
    for (int c = 0; c < W; ++c) t[c] = fast_tanh(y[c]);

    float yt[W], yb[W];
#pragma unroll
    for (int c = 0; c < W; ++c) { yt[c] = bpi0[c]; yb[c] = 0.0f; }
#pragma unroll
    for (int k = 0; k < W; ++k)
#pragma unroll
        for (int c = 0; c < W; ++c) {
            yt[c] += t[k] * Wpi0[k*W + c];
            yb[c] += t[k] * Wpi0[(W + k)*W + c];
        }
    float4* dt = reinterpret_cast<float4*>(ytop + (size_t)a * W);
    float4* db = reinterpret_cast<float4*>(ybot + (size_t)a * W);
#pragma unroll
    for (int q = 0; q < 4; ++q) {
        dt[q] = make_float4(SC*yt[4*q], SC*yt[4*q+1], SC*yt[4*q+2], SC*yt[4*q+3]);
        db[q] = make_float4(SC*yb[4*q], SC*yb[4*q+1], SC*yb[4*q+2], SC*yb[4*q+3]);
    }
}

// ---------------- pair kernel: 32x32x16 MFMA, one 32-pair super per wave-iter
// pi1 packing: tile T, A-row: ch = 4*(row>>3)+(row&3), bp = 2T+((row>>2)&1)
// => C-reg i (row=(i&3)+8*(i>>2)+4h): ch = i, bp = 2T+h  (all static)
template<int USE_RANK>
__global__ __launch_bounds__(256) void k_pair_mfma(
    const int*   __restrict__ ind2,
    const float* __restrict__ basis,
    const float* __restrict__ ytop,
    const float* __restrict__ ybot,
    const float* __restrict__ Wpi1, const float* __restrict__ bpi1,
    const float* __restrict__ Wii0, const float* __restrict__ Wii1,
    float* __restrict__ i_pair_out,
    const unsigned* __restrict__ starts,
    const unsigned* __restrict__ rank,
    unsigned* __restrict__ cursor,
    float* __restrict__ svals)
{
    __shared__ s16x8 aw_lds[5][2][32];   // Wpi1 tiles  [T][h][row]
    __shared__ s16x8 ab_lds[5][2][32];   // bias tiles (rank-1, k==0 column)

    const int lane = threadIdx.x & 63;
    const int wv   = threadIdx.x >> 6;
    const int col  = lane & 31;     // pair slot within super
    const int h    = lane >> 5;     // k-half

    for (int e = threadIdx.x; e < 320; e += 256) {
        int T = e >> 6, hh = (e >> 5) & 1, row = e & 31;
        int colW = (4*(row >> 3) + (row & 3)) * N_BASIS + 2*T + ((row >> 2) & 1);
        s16x8 wfrag, bfrag;
#pragma unroll
        for (int j = 0; j < 8; ++j) {
            int k = 8*hh + j;
            wfrag[j] = (short)bf16r(SC * Wpi1[k*(W*N_BASIS) + colW]);
            bfrag[j] = (short)((k == 0) ? bf16r(SC * bpi1[colW]) : 0);
        }
        aw_lds[T][hh][row] = wfrag;
        ab_lds[T][hh][row] = bfrag;
    }

    s16x8 a3, a4;
#pragma unroll
    for (int j = 0; j < 8; ++j) {
        int k = 8*h + j;
        a3[j] = (short)(col < W ? bf16r(SC * Wii0[k*W + col]) : 0);
        a4[j] = (short)(col < W ? bf16r(SC * Wii1[k*W + col]) : 0);
    }
    s16x8 Bones = {0,0,0,0,0,0,0,0};
    if (h == 0) Bones[0] = (short)0x3F80;   // bf16(1.0) at k==0

    __syncthreads();

    const int stride = gridDim.x * 4;
    int sup = blockIdx.x * 4 + wv;
    if (sup >= NSUP) return;
    const int2* ind2v = reinterpret_cast<const int2*>(ind2);

    // prologue
    int2 ij = ind2v[(size_t)sup * 32 + col];
    f32x4 yt0 = *reinterpret_cast<const f32x4*>(ytop + (size_t)ij.x * W + 8*h);
    f32x4 yt1 = *reinterpret_cast<const f32x4*>(ytop + (size_t)ij.x * W + 8*h + 4);
    f32x4 yb0 = *reinterpret_cast<const f32x4*>(ybot + (size_t)ij.y * W + 8*h);
    f32x4 yb1 = *reinterpret_cast<const f32x4*>(ybot + (size_t)ij.y * W + 8*h + 4);

    for (; sup < NSUP; sup += stride) {
        const int p = sup * 32 + col;
        const int nsup = (sup + stride < NSUP) ? (sup + stride) : sup;

        // (1) issue next ind2 load
        int2 nij = ind2v[(size_t)nsup * 32 + col];

        // (2) pi0: lane's own 8-ch half, no shuffles
        float h0[8];
#pragma unroll
        for (int j = 0; j < 4; ++j) h0[j]     = tanh_pre(yt0[j] + yb0[j]);
#pragma unroll
        for (int j = 0; j < 4; ++j) h0[4 + j] = tanh_pre(yt1[j] + yb1[j]);
        unsigned w0h = cvt_pk_bf16(h0[0], h0[1]);
        unsigned w1h = cvt_pk_bf16(h0[2], h0[3]);
        unsigned w2h = cvt_pk_bf16(h0[4], h0[5]);
        unsigned w3h = cvt_pk_bf16(h0[6], h0[7]);
        unsigned w0l = cvt_pk_bf16(h0[0] - bitf(w0h << 16), h0[1] - bitf(w0h & 0xFFFF0000u));
        unsigned w1l = cvt_pk_bf16(h0[2] - bitf(w1h << 16), h0[3] - bitf(w1h & 0xFFFF0000u));
        unsigned w2l = cvt_pk_bf16(h0[4] - bitf(w2h << 16), h0[5] - bitf(w2h & 0xFFFF0000u));
        unsigned w3l = cvt_pk_bf16(h0[6] - bitf(w3h << 16), h0[7] - bitf(w3h & 0xFFFF0000u));
        union { unsigned u[4]; s16x8 v; } BH, BL;
        BH.u[0] = w0h; BH.u[1] = w1h; BH.u[2] = w2h; BH.u[3] = w3h;
        BL.u[0] = w0l; BL.u[1] = w1l; BL.u[2] = w2l; BL.u[3] = w3l;
        s16x8 B2h = BH.v, B2l = BL.v;

        // (3) basis: 5 float2 loads + half-select
        const float2* bb = reinterpret_cast<const float2*>(basis + (size_t)p * N_BASIS);
        float bsel[5];
#pragma unroll
        for (int q = 0; q < 5; ++q) {
            float2 t2 = bb[q];
            bsel[q] = h ? t2.y : t2.x;   // bas[2q+h]
        }

        // (4) pi1: 5 tiles x (bias + hi + lo) MFMA, static epilogue (ch = reg i)
        float v[16];
#pragma unroll
        for (int i = 0; i < 16; ++i) v[i] = 0.0f;
#pragma unroll
        for (int T = 0; T < 5; ++T) {
            s16x8 af = aw_lds[T][h][col];
            s16x8 ab = ab_lds[T][h][col];
            f32x16 z = {0.0f};
            z = __builtin_amdgcn_mfma_f32_32x32x16_bf16(ab, Bones, z, 0, 0, 0);
            z = __builtin_amdgcn_mfma_f32_32x32x16_bf16(af, B2h,  z, 0, 0, 0);
            z = __builtin_amdgcn_mfma_f32_32x32x16_bf16(af, B2l,  z, 0, 0, 0);
#pragma unroll
            for (int i = 0; i < 16; ++i)
                v[i] += tanh_pre(z[i]) * bsel[T];
        }

        // (5) issue next gathers (nij landed under pi1)
        f32x4 nyt0 = *reinterpret_cast<const f32x4*>(ytop + (size_t)nij.x * W + 8*h);
        f32x4 nyt1 = *reinterpret_cast<const f32x4*>(ytop + (size_t)nij.x * W + 8*h + 4);
        f32x4 nyb0 = *reinterpret_cast<const f32x4*>(ybot + (size_t)nij.y * W + 8*h);
        f32x4 nyb1 = *reinterpret_cast<const f32x4*>(ybot + (size_t)nij.y * W + 8*h + 4);

        // (6) combine bp-halves of v across lane halves (need full v[8h+j])
        float own[8], snd[8];
        if (h == 0) {
#pragma unroll
            for (int j = 0; j < 8; ++j) { own[j] = v[j]; snd[j] = v[8 + j]; }
        } else {
#pragma unroll
            for (int j = 0; j < 8; ++j) { own[j] = v[8 + j]; snd[j] = v[j]; }
        }
        float vf[8];
#pragma unroll
        for (int j = 0; j < 8; ++j) vf[j] = own[j] + __shfl_xor(snd[j], 32);

        // (7) ii0
        union { unsigned u[4]; s16x8 v; } B3u;
        B3u.u[0] = cvt_pk_bf16(vf[0], vf[1]);
        B3u.u[1] = cvt_pk_bf16(vf[2], vf[3]);
        B3u.u[2] = cvt_pk_bf16(vf[4], vf[5]);
        B3u.u[3] = cvt_pk_bf16(vf[6], vf[7]);
        f32x16 ua = {0.0f};
        ua = __builtin_amdgcn_mfma_f32_32x32x16_bf16(a3, B3u.v, ua, 0, 0, 0);
        float u[8];
#pragma unroll
        for (int i = 0; i < 8; ++i) u[i] = tanh_pre(ua[i]);   // rows {0-3,8-11}+4h

        // (8) ii1: swap quads so each lane holds u[8h..8h+7]
        float uo[4], us[4];
        if (h == 0) {
#pragma unroll
            for (int j = 0; j < 4; ++j) { uo[j] = u[j]; us[j] = u[4 + j]; }   // own rows 0-3, send 8-11
        } else {
#pragma unroll
            for (int j = 0; j < 4; ++j) { uo[j] = u[4 + j]; us[j] = u[j]; }   // own rows 12-15, send 4-7
        }
        float ur[4];
#pragma unroll
        for (int j = 0; j < 4; ++j) ur[j] = __shfl_xor(us[j], 32);
        union { unsigned u[4]; s16x8 v; } B4u;
        if (h == 0) {   // k 0..7 = [own(0-3), recv(4-7)]
            B4u.u[0] = cvt_pk_bf16(uo[0], uo[1]);
            B4u.u[1] = cvt_pk_bf16(uo[2], uo[3]);
            B4u.u[2] = cvt_pk_bf16(ur[0], ur[1]);
            B4u.u[3] = cvt_pk_bf16(ur[2], ur[3]);
        } else {        // k 8..15 = [recv(8-11), own(12-15)]
            B4u.u[0] = cvt_pk_bf16(ur[0], ur[1]);
            B4u.u[1] = cvt_pk_bf16(ur[2], ur[3]);
            B4u.u[2] = cvt_pk_bf16(uo[0], uo[1]);
            B4u.u[3] = cvt_pk_bf16(uo[2], uo[3]);
        }
        f32x16 wa = {0.0f};
        wa = __builtin_amdgcn_mfma_f32_32x32x16_bf16(a4, B4u.v, wa, 0, 0, 0);
        float wq[8];
#pragma unroll
        for (int i = 0; i < 8; ++i) wq[i] = tanh_pre(wa[i]);

        // (9) stores: lane h=0 covers ch{0-3,8-11}, h=1 ch{4-7,12-15}
        const int off1 = h ? 4 : 0;
        const int off2 = h ? 12 : 8;
        float* ob = i_pair_out + (size_t)p * W;
        nt_store4(ob + off1, wq[0], wq[1], wq[2], wq[3]);
        nt_store4(ob + off2, wq[4], wq[5], wq[6], wq[7]);

        unsigned pos;
        if (USE_RANK) {
            pos = starts[ij.x] + rank[p];
        } else {
            unsigned pp = 0;
            if (h == 0) pp = atomicAdd(&cursor[ij.x], 1u);
            pos = (unsigned)__shfl((int)pp, col);
        }
        float* sb = svals + (size_t)pos * W;
        nt_store4(sb + off1, wq[0], wq[1], wq[2], wq[3]);
        nt_store4(sb + off2, wq[4], wq[5], wq[6], wq[7]);

        // (10) rotate
        ij = nij;
        yt0 = nyt0; yt1 = nyt1; yb0 = nyb0; yb1 = nyb1;
    }
}

// ---------------- IP pipeline
__global__ __launch_bounds__(256) void k_count(const int* __restrict__ ind2,
                                               unsigned* __restrict__ counts,
                                               unsigned* __restrict__ rank)
{
    int p = blockIdx.x * 256 + threadIdx.x;
    if (p >= N_PAIRS) return;
    rank[p] = atomicAdd(&counts[ind2[2*p]], 1u);
}

__global__ __launch_bounds__(SCAN_BLK) void k_scanA(const unsigned* __restrict__ counts,
                                                    unsigned* __restrict__ starts,
                                                    unsigned* __restrict__ bsum)
{
    __shared__ unsigned sc[SCAN_BLK];
    int a = blockIdx.x * SCAN_BLK + threadIdx.x;
    unsigned c = (a < N_ATOMS) ? counts[a] : 0u;
    sc[threadIdx.x] = c;
    __syncthreads();
    for (int off = 1; off < SCAN_BLK; off <<= 1) {
        unsigned v = sc[threadIdx.x];
        unsigned add = (threadIdx.x >= off) ? sc[threadIdx.x - off] : 0u;
        __syncthreads();
        sc[threadIdx.x] = v + add;
        __syncthreads();
    }
    if (a < N_ATOMS) starts[a] = sc[threadIdx.x] - c;
    if (threadIdx.x == SCAN_BLK - 1) bsum[blockIdx.x] = sc[SCAN_BLK - 1];
}

__global__ __launch_bounds__(128) void k_scanB(const unsigned* __restrict__ bsum,
                                               unsigned* __restrict__ boff)
{
    __shared__ unsigned s[128];
    int t = threadIdx.x;
    unsigned v = (t < NB) ? bsum[t] : 0u;
    s[t] = v;
    __syncthreads();
    for (int off = 1; off < 128; off <<= 1) {
        unsigned x = s[t];
        unsigned add = (t >= off) ? s[t - off] : 0u;
        __syncthreads();
        s[t] = x + add;
        __syncthreads();
    }
    if (t < NB) boff[t] = s[t] - v;
}

__global__ __launch_bounds__(SCAN_BLK) void k_scanC(unsigned* __restrict__ starts,
                                                    const unsigned* __restrict__ boff,
                                                    unsigned* __restrict__ cursor)
{
    int a = blockIdx.x * SCAN_BLK + threadIdx.x;
    if (a >= N_ATOMS) return;
    unsigned s = starts[a] + boff[blockIdx.x];
    starts[a] = s;
    cursor[a] = s;
}

__global__ __launch_bounds__(256) void k_reduce_stream(const unsigned* __restrict__ starts,
                                                       const unsigned* __restrict__ counts,
                                                       const float* __restrict__ svals,
                                                       float* __restrict__ p_sum)
{
    int a = blockIdx.x * 4 + (threadIdx.x >> 6);
    if (a >= N_ATOMS) return;
    int lane = threadIdx.x & 63;
    int c = lane & 15, q = lane >> 4;
    unsigned n = counts[a], st = starts[a];
    float acc = 0.0f;
    for (unsigned k = q; k < n; k += 4)
        acc += svals[(size_t)(st + k) * W + c];
    acc += __shfl_xor(acc, 16);
    acc += __shfl_xor(acc, 32);
    if (q == 0) p_sum[(size_t)a * W + c] = acc;
}

// ---------------- pp_post
__global__ __launch_bounds__(256) void k_pp_post(
    const float* __restrict__ p_sum,
    const float* __restrict__ W0, const float* __restrict__ W1,
    float* __restrict__ p1_new)
{
    int a = blockIdx.x * 256 + threadIdx.x;
    if (a >= N_ATOMS) return;
    const float4* src = reinterpret_cast<const float4*>(p_sum + (size_t)a * W);
    float4 v0 = src[0], v1 = src[1], v2 = src[2], v3 = src[3];
    float x[W] = {v0.x,v0.y,v0.z,v0.w, v1.x,v1.y,v1.z,v1.w,
                  v2.x,v2.y,v2.z,v2.w, v3.x,v3.y,v3.z,v3.w};
    float h[W];
#pragma unroll
    for (int c = 0; c < W; ++c) h[c] = 0.0f;
#pragma unroll
    for (int k = 0; k < W; ++k)
#pragma unroll
        for (int c = 0; c < W; ++c) h[c] += x[k] * W0[k*W + c];
#pragma unroll
    for (int c = 0; c < W; ++c) h[c] = fast_tanh(h[c]);
    float y[W];
#pragma unroll
    for (int c = 0; c < W; ++c) y[c] = 0.0f;
#pragma unroll
    for (int k = 0; k < W; ++k)
#pragma unroll
        for (int c = 0; c < W; ++c) y[c] += h[k] * W1[k*W + c];
    float4* dst = reinterpret_cast<float4*>(p1_new + (size_t)a * W);
    dst[0] = make_float4(fast_tanh(y[0]),  fast_tanh(y[1]),  fast_tanh(y[2]),  fast_tanh(y[3]));
    dst[1] = make_float4(fast_tanh(y[4]),  fast_tanh(y[5]),  fast_tanh(y[6]),  fast_tanh(y[7]));
    dst[2] = make_float4(fast_tanh(y[8]),  fast_tanh(y[9]),  fast_tanh(y[10]), fast_tanh(y[11]));
    dst[3] = make_float4(fast_tanh(y[12]), fast_tanh(y[13]), fast_tanh(y[14]), fast_tanh(y[15]));
}

extern "C" void kernel_launch(void* const* d_in, const int* in_sizes, int n_in,
                              void* d_out, int out_size, void* d_ws, size_t ws_size,
                              hipStream_t stream) {
    const int*   ind2   = (const int*)d_in[0];
    const float* p1     = (const float*)d_in[1];
    const float* basis  = (const float*)d_in[2];
    const float* Wpre0  = (const float*)d_in[3];
    const float* bpre0  = (const float*)d_in[4];
    const float* Wpre1  = (const float*)d_in[5];
    const float* bpre1  = (const float*)d_in[6];
    const float* Wpi0   = (const float*)d_in[7];
    const float* bpi0   = (const float*)d_in[8];
    const float* Wpi1   = (const float*)d_in[9];
    const float* bpi1   = (const float*)d_in[10];
    const float* Wii0   = (const float*)d_in[11];
    const float* Wii1   = (const float*)d_in[12];
    const float* Wpost0 = (const float*)d_in[13];
    const float* Wpost1 = (const float*)d_in[14];

    float* out    = (float*)d_out;
    float* p1_new = out;                          // (N_ATOMS, W)
    float* i_pair = out + (size_t)N_ATOMS * W;    // (N_PAIRS, W)

    char* ws = (char*)d_ws;
    float*    ytop   = (float*)ws;                                ws += (size_t)N_ATOMS * W * 4;
    float*    ybot   = (float*)ws;                                ws += (size_t)N_ATOMS * W * 4;
    float*    p_sum  = (float*)ws;                                ws += (size_t)N_ATOMS * W * 4;
    unsigned* counts = (unsigned*)ws;                             ws += (size_t)N_ATOMS * 4;
    unsigned* starts = (unsigned*)ws;                             ws += (size_t)N_ATOMS * 4;
    unsigned* cursor = (unsigned*)ws;                             ws += (size_t)N_ATOMS * 4;
    unsigned* bsum   = (unsigned*)ws;                             ws += 1024 * 4;
    unsigned* boff   = (unsigned*)ws;                             ws += 1024 * 4;
    float*    svals  = (float*)ws;                                ws += (size_t)N_PAIRS * W * 4;
    unsigned* rank   = (unsigned*)ws;                             ws += (size_t)N_PAIRS * 4;

    int use_rank = (ws_size >= (size_t)(ws - (char*)d_ws));

    hipMemsetAsync(counts, 0, (size_t)N_ATOMS * sizeof(unsigned), stream);
    k_pp_pre<<<(N_ATOMS + 255) / 256, 256, 0, stream>>>(p1, Wpre0, bpre0, Wpre1, bpre1,
                                                        Wpi0, bpi0, ytop, ybot);
    k_count<<<(N_PAIRS + 255) / 256, 256, 0, stream>>>(ind2, counts, use_rank ? rank : cursor);
    k_scanA<<<NB, SCAN_BLK, 0, stream>>>(counts, starts, bsum);
    k_scanB<<<1, 128, 0, stream>>>(bsum, boff);
    k_scanC<<<NB, SCAN_BLK, 0, stream>>>(starts, boff, cursor);

    if (use_rank) {
        k_pair_mfma<1><<<2560, 256, 0, stream>>>(ind2, basis, ytop, ybot,
                                                 Wpi1, bpi1, Wii0, Wii1,
                                                 i_pair, starts, rank, cursor, svals);
    } else {
        k_pair_mfma<0><<<2560, 256, 0, stream>>>(ind2, basis, ytop, ybot,
                                                 Wpi1, bpi1, Wii0, Wii1,
                                                 i_pair, starts, rank, cursor, svals);
    }
    k_reduce_stream<<<(N_ATOMS + 3) / 4, 256, 0, stream>>>(starts, counts, svals, p_sum);
    k_pp_post<<<(N_ATOMS + 255) / 256, 256, 0, stream>>>(p_sum, Wpost0, Wpost1, p1_new);
}

// Round 10
// 484.736 us; speedup vs baseline: 1.5171x; 1.1314x over previous
//
#include <hip/hip_runtime.h>

#define N_ATOMS 100000
#define N_PAIRS 3200000
#define N_PROP 16
#define N_BASIS 10
#define W 16
#define NSUP (N_PAIRS / 32)   // 100000 supers, 32 pairs each
#define SCAN_BLK 1024
#define NB ((N_ATOMS + SCAN_BLK - 1) / SCAN_BLK)   // 98
#define SC 2.88539008177792681f   // 2*log2(e), folded into weights/pre-acts

typedef short  s16x8  __attribute__((ext_vector_type(8)));
typedef float  f32x4  __attribute__((ext_vector_type(4)));
typedef float  f32x16 __attribute__((ext_vector_type(16)));

__device__ __forceinline__ float tanh_pre(float y) {   // y = SC*x
    float e = __builtin_amdgcn_exp2f(y);
    return 1.0f - 2.0f * __builtin_amdgcn_rcpf(e + 1.0f);
}
__device__ __forceinline__ float fast_tanh(float x) {
    float e = __builtin_amdgcn_exp2f(x * SC);
    return 1.0f - 2.0f * __builtin_amdgcn_rcpf(e + 1.0f);
}
__device__ __forceinline__ unsigned short bf16r(float f) {
    union { float f; unsigned u; } v; v.f = f;
    unsigned r = v.u + 0x7FFFu + ((v.u >> 16) & 1u);
    return (unsigned short)(r >> 16);
}
__device__ __forceinline__ unsigned cvt_pk_bf16(float a, float b) {
    unsigned r;
    asm("v_cvt_pk_bf16_f32 %0, %1, %2" : "=v"(r) : "v"(a), "v"(b));
    return r;   // low16 = bf16(a), high16 = bf16(b), RTNE
}
__device__ __forceinline__ float bitf(unsigned u) {
    union { unsigned u; float f; } v; v.u = u; return v.f;
}

// ---------------- pp_pre: fused pi0 per-atom halves (f32, SC+bias folded)
__global__ __launch_bounds__(256) void k_pp_pre(
    const float* __restrict__ p1,
    const float* __restrict__ W0, const float* __restrict__ b0,
    const float* __restrict__ W1, const float* __restrict__ b1,
    const float* __restrict__ Wpi0, const float* __restrict__ bpi0,
    float* __restrict__ ytop, float* __restrict__ ybot)
{
    int a = blockIdx.x * 256 + threadIdx.x;
    if (a >= N_ATOMS) return;
    const float4* src = reinterpret_cast<const float4*>(p1 + (size_t)a * N_PROP);
    float4 v0 = src[0], v1 = src[1], v2 = src[2], v3 = src[3];
    float x[N_PROP] = {v0.x,v0.y,v0.z,v0.w, v1.x,v1.y,v1.z,v1.w,
                       v2.x,v2.y,v2.z,v2.w, v3.x,v3.y,v3.z,v3.w};
    float h[W];
#pragma unroll
    for (int c = 0; c < W; ++c) h[c] = b0[c];
#pragma unroll
    for (int k = 0; k < N_PROP; ++k)
#pragma unroll
        for (int c = 0; c < W; ++c) h[c] += x[k] * W0[k*W + c];
#pragma unroll
    for (int c = 0; c < W; ++c) h[c] = fast_tanh(h[c]);
    float y[W];
#pragma unroll
    for (int c = 0; c < W; ++c) y[c] = b1[c];
#pragma unroll
    for (int k = 0; k < W; ++k)
#pragma unroll
        for (int c = 0; c < W; ++c) y[c] += h[k] * W1[k*W + c];
    float t[W];
#pragma unroll
    for (int c = 0; c < W; ++c) t[c] = fast_tanh(y[c]);

    float yt[W], yb[W];
#pragma unroll
    for (int c = 0; c < W; ++c) { yt[c] = bpi0[c]; yb[c] = 0.0f; }
#pragma unroll
    for (int k = 0; k < W; ++k)
#pragma unroll
        for (int c = 0; c < W; ++c) {
            yt[c] += t[k] * Wpi0[k*W + c];
            yb[c] += t[k] * Wpi0[(W + k)*W + c];
        }
    float4* dt = reinterpret_cast<float4*>(ytop + (size_t)a * W);
    float4* db = reinterpret_cast<float4*>(ybot + (size_t)a * W);
#pragma unroll
    for (int q = 0; q < 4; ++q) {
        dt[q] = make_float4(SC*yt[4*q], SC*yt[4*q+1], SC*yt[4*q+2], SC*yt[4*q+3]);
        db[q] = make_float4(SC*yb[4*q], SC*yb[4*q+1], SC*yb[4*q+2], SC*yb[4*q+3]);
    }
}

// ---------------- pair kernel: 32x32x16 MFMA, one 32-pair super per wave-iter
// pi1 packing: tile T, A-row: ch = 4*(row>>3)+(row&3), bp = 2T+((row>>2)&1)
// => C-reg i (row=(i&3)+8*(i>>2)+4h): ch = i, bp = 2T+h  (all static)
template<int USE_RANK>
__global__ __launch_bounds__(256) void k_pair_mfma(
    const int*   __restrict__ ind2,
    const float* __restrict__ basis,
    const float* __restrict__ ytop,
    const float* __restrict__ ybot,
    const float* __restrict__ Wpi1, const float* __restrict__ bpi1,
    const float* __restrict__ Wii0, const float* __restrict__ Wii1,
    float* __restrict__ i_pair_out,
    const unsigned* __restrict__ starts,
    const unsigned* __restrict__ rank,
    unsigned* __restrict__ cursor,
    float* __restrict__ svals)
{
    __shared__ s16x8 aw_lds[5][2][32];   // Wpi1 tiles  [T][h][row]
    __shared__ s16x8 ab_lds[5][2][32];   // bias tiles (rank-1, k==0 column)

    const int lane = threadIdx.x & 63;
    const int wv   = threadIdx.x >> 6;
    const int col  = lane & 31;     // pair slot within super
    const int h    = lane >> 5;     // k-half

    for (int e = threadIdx.x; e < 320; e += 256) {
        int T = e >> 6, hh = (e >> 5) & 1, row = e & 31;
        int colW = (4*(row >> 3) + (row & 3)) * N_BASIS + 2*T + ((row >> 2) & 1);
        s16x8 wfrag, bfrag;
#pragma unroll
        for (int j = 0; j < 8; ++j) {
            int k = 8*hh + j;
            wfrag[j] = (short)bf16r(SC * Wpi1[k*(W*N_BASIS) + colW]);
            bfrag[j] = (short)((k == 0) ? bf16r(SC * bpi1[colW]) : 0);
        }
        aw_lds[T][hh][row] = wfrag;
        ab_lds[T][hh][row] = bfrag;
    }

    s16x8 a3, a4;
#pragma unroll
    for (int j = 0; j < 8; ++j) {
        int k = 8*h + j;
        a3[j] = (short)(col < W ? bf16r(SC * Wii0[k*W + col]) : 0);
        a4[j] = (short)(col < W ? bf16r(SC * Wii1[k*W + col]) : 0);
    }
    s16x8 Bones = {0,0,0,0,0,0,0,0};
    if (h == 0) Bones[0] = (short)0x3F80;   // bf16(1.0) at k==0

    __syncthreads();

    const int stride = gridDim.x * 4;
    int sup = blockIdx.x * 4 + wv;
    if (sup >= NSUP) return;
    const int2* ind2v = reinterpret_cast<const int2*>(ind2);

    // prologue
    int2 ij = ind2v[(size_t)sup * 32 + col];
    f32x4 yt0 = *reinterpret_cast<const f32x4*>(ytop + (size_t)ij.x * W + 8*h);
    f32x4 yt1 = *reinterpret_cast<const f32x4*>(ytop + (size_t)ij.x * W + 8*h + 4);
    f32x4 yb0 = *reinterpret_cast<const f32x4*>(ybot + (size_t)ij.y * W + 8*h);
    f32x4 yb1 = *reinterpret_cast<const f32x4*>(ybot + (size_t)ij.y * W + 8*h + 4);

    for (; sup < NSUP; sup += stride) {
        const int p0 = sup * 32;
        const int p  = p0 + col;
        const int nsup = (sup + stride < NSUP) ? (sup + stride) : sup;

        // (1) issue next ind2 load
        int2 nij = ind2v[(size_t)nsup * 32 + col];

        // (2) pi0: lane's own 8-ch half, no shuffles
        float h0[8];
#pragma unroll
        for (int j = 0; j < 4; ++j) h0[j]     = tanh_pre(yt0[j] + yb0[j]);
#pragma unroll
        for (int j = 0; j < 4; ++j) h0[4 + j] = tanh_pre(yt1[j] + yb1[j]);
        unsigned w0h = cvt_pk_bf16(h0[0], h0[1]);
        unsigned w1h = cvt_pk_bf16(h0[2], h0[3]);
        unsigned w2h = cvt_pk_bf16(h0[4], h0[5]);
        unsigned w3h = cvt_pk_bf16(h0[6], h0[7]);
        unsigned w0l = cvt_pk_bf16(h0[0] - bitf(w0h << 16), h0[1] - bitf(w0h & 0xFFFF0000u));
        unsigned w1l = cvt_pk_bf16(h0[2] - bitf(w1h << 16), h0[3] - bitf(w1h & 0xFFFF0000u));
        unsigned w2l = cvt_pk_bf16(h0[4] - bitf(w2h << 16), h0[5] - bitf(w2h & 0xFFFF0000u));
        unsigned w3l = cvt_pk_bf16(h0[6] - bitf(w3h << 16), h0[7] - bitf(w3h & 0xFFFF0000u));
        union { unsigned u[4]; s16x8 v; } BH, BL;
        BH.u[0] = w0h; BH.u[1] = w1h; BH.u[2] = w2h; BH.u[3] = w3h;
        BL.u[0] = w0l; BL.u[1] = w1l; BL.u[2] = w2l; BL.u[3] = w3l;
        s16x8 B2h = BH.v, B2l = BL.v;

        // (3) basis: 5 float2 loads + half-select
        const float2* bb = reinterpret_cast<const float2*>(basis + (size_t)p * N_BASIS);
        float bsel[5];
#pragma unroll
        for (int q = 0; q < 5; ++q) {
            float2 t2 = bb[q];
            bsel[q] = h ? t2.y : t2.x;   // bas[2q+h]
        }

        // (4) pi1: 5 tiles x (bias + hi + lo) MFMA, static epilogue (ch = reg i)
        float v[16];
#pragma unroll
        for (int i = 0; i < 16; ++i) v[i] = 0.0f;
#pragma unroll
        for (int T = 0; T < 5; ++T) {
            s16x8 af = aw_lds[T][h][col];
            s16x8 ab = ab_lds[T][h][col];
            f32x16 z = {0.0f};
            z = __builtin_amdgcn_mfma_f32_32x32x16_bf16(ab, Bones, z, 0, 0, 0);
            z = __builtin_amdgcn_mfma_f32_32x32x16_bf16(af, B2h,  z, 0, 0, 0);
            z = __builtin_amdgcn_mfma_f32_32x32x16_bf16(af, B2l,  z, 0, 0, 0);
#pragma unroll
            for (int i = 0; i < 16; ++i)
                v[i] += tanh_pre(z[i]) * bsel[T];
        }

        // (5) issue next gathers (nij landed under pi1)
        f32x4 nyt0 = *reinterpret_cast<const f32x4*>(ytop + (size_t)nij.x * W + 8*h);
        f32x4 nyt1 = *reinterpret_cast<const f32x4*>(ytop + (size_t)nij.x * W + 8*h + 4);
        f32x4 nyb0 = *reinterpret_cast<const f32x4*>(ybot + (size_t)nij.y * W + 8*h);
        f32x4 nyb1 = *reinterpret_cast<const f32x4*>(ybot + (size_t)nij.y * W + 8*h + 4);

        // (6) combine bp-halves of v across lane halves (need full v[8h+j])
        float own[8], snd[8];
        if (h == 0) {
#pragma unroll
            for (int j = 0; j < 8; ++j) { own[j] = v[j]; snd[j] = v[8 + j]; }
        } else {
#pragma unroll
            for (int j = 0; j < 8; ++j) { own[j] = v[8 + j]; snd[j] = v[j]; }
        }
        float vf[8];
#pragma unroll
        for (int j = 0; j < 8; ++j) vf[j] = own[j] + __shfl_xor(snd[j], 32);

        // (7) ii0
        union { unsigned u[4]; s16x8 v; } B3u;
        B3u.u[0] = cvt_pk_bf16(vf[0], vf[1]);
        B3u.u[1] = cvt_pk_bf16(vf[2], vf[3]);
        B3u.u[2] = cvt_pk_bf16(vf[4], vf[5]);
        B3u.u[3] = cvt_pk_bf16(vf[6], vf[7]);
        f32x16 ua = {0.0f};
        ua = __builtin_amdgcn_mfma_f32_32x32x16_bf16(a3, B3u.v, ua, 0, 0, 0);
        float u[8];
#pragma unroll
        for (int i = 0; i < 8; ++i) u[i] = tanh_pre(ua[i]);   // rows {0-3,8-11}+4h

        // (8) ii1: swap quads so each lane holds u[8h..8h+7]
        float uo[4], us[4];
        if (h == 0) {
#pragma unroll
            for (int j = 0; j < 4; ++j) { uo[j] = u[j]; us[j] = u[4 + j]; }
        } else {
#pragma unroll
            for (int j = 0; j < 4; ++j) { uo[j] = u[4 + j]; us[j] = u[j]; }
        }
        float ur[4];
#pragma unroll
        for (int j = 0; j < 4; ++j) ur[j] = __shfl_xor(us[j], 32);
        union { unsigned u[4]; s16x8 v; } B4u;
        if (h == 0) {
            B4u.u[0] = cvt_pk_bf16(uo[0], uo[1]);
            B4u.u[1] = cvt_pk_bf16(uo[2], uo[3]);
            B4u.u[2] = cvt_pk_bf16(ur[0], ur[1]);
            B4u.u[3] = cvt_pk_bf16(ur[2], ur[3]);
        } else {
            B4u.u[0] = cvt_pk_bf16(ur[0], ur[1]);
            B4u.u[1] = cvt_pk_bf16(ur[2], ur[3]);
            B4u.u[2] = cvt_pk_bf16(uo[0], uo[1]);
            B4u.u[3] = cvt_pk_bf16(uo[2], uo[3]);
        }
        f32x16 wa = {0.0f};
        wa = __builtin_amdgcn_mfma_f32_32x32x16_bf16(a4, B4u.v, wa, 0, 0, 0);
        float wq[8];
#pragma unroll
        for (int i = 0; i < 8; ++i) wq[i] = tanh_pre(wa[i]);
        // lane (col,h0): wq[0..3]=ch0-3, wq[4..7]=ch8-11 of pair col
        // lane (col,h1): wq[0..3]=ch4-7, wq[4..7]=ch12-15

        // pos for own pair col
        unsigned pos;
        if (USE_RANK) {
            pos = starts[ij.x] + rank[p];
        } else {
            unsigned pp = 0;
            if (h == 0) pp = atomicAdd(&cursor[ij.x], 1u);
            pos = (unsigned)__shfl((int)pp, col);
        }

        // (9) full-cache-line cooperative stores:
        // instr k: lane -> row 16k+(lane&15), quarter q=lane>>4 (ch 4q..4q+3)
        const int rk0 = lane & 15;
        const int q   = lane >> 4;
#pragma unroll
        for (int k = 0; k < 2; ++k) {
            int row = 16*k + rk0;
            int src = row + 32*(q & 1);    // q even -> h0 lane, q odd -> h1 lane
            float vA0 = __shfl(wq[0], src), vA1 = __shfl(wq[1], src);
            float vA2 = __shfl(wq[2], src), vA3 = __shfl(wq[3], src);
            float vB0 = __shfl(wq[4], src), vB1 = __shfl(wq[5], src);
            float vB2 = __shfl(wq[6], src), vB3 = __shfl(wq[7], src);
            bool hiq = (q >= 2);
            f32x4 val = { hiq ? vB0 : vA0, hiq ? vB1 : vA1,
                          hiq ? vB2 : vA2, hiq ? vB3 : vA3 };
            unsigned posr = (unsigned)__shfl((int)pos, row);
            __builtin_nontemporal_store(val,
                reinterpret_cast<f32x4*>(i_pair_out + (size_t)(p0 + row) * W + q*4));
            __builtin_nontemporal_store(val,
                reinterpret_cast<f32x4*>(svals + (size_t)posr * W + q*4));
        }

        // (10) rotate
        ij = nij;
        yt0 = nyt0; yt1 = nyt1; yb0 = nyb0; yb1 = nyb1;
    }
}

// ---------------- IP pipeline
__global__ __launch_bounds__(256) void k_count(const int* __restrict__ ind2,
                                               unsigned* __restrict__ counts,
                                               unsigned* __restrict__ rank)
{
    int t = blockIdx.x * 256 + threadIdx.x;
    if (t >= N_PAIRS / 2) return;
    int4 ii = reinterpret_cast<const int4*>(ind2)[t];   // pairs 2t (x,y), 2t+1 (z,w)
    unsigned r0 = atomicAdd(&counts[ii.x], 1u);
    unsigned r1 = atomicAdd(&counts[ii.z], 1u);
    uint2 rr; rr.x = r0; rr.y = r1;
    *reinterpret_cast<uint2*>(rank + 2*t) = rr;
}

__global__ __launch_bounds__(SCAN_BLK) void k_scanA(const unsigned* __restrict__ counts,
                                                    unsigned* __restrict__ starts,
                                                    unsigned* __restrict__ bsum)
{
    __shared__ unsigned sc[SCAN_BLK];
    int a = blockIdx.x * SCAN_BLK + threadIdx.x;
    unsigned c = (a < N_ATOMS) ? counts[a] : 0u;
    sc[threadIdx.x] = c;
    __syncthreads();
    for (int off = 1; off < SCAN_BLK; off <<= 1) {
        unsigned v = sc[threadIdx.x];
        unsigned add = (threadIdx.x >= off) ? sc[threadIdx.x - off] : 0u;
        __syncthreads();
        sc[threadIdx.x] = v + add;
        __syncthreads();
    }
    if (a < N_ATOMS) starts[a] = sc[threadIdx.x] - c;
    if (threadIdx.x == SCAN_BLK - 1) bsum[blockIdx.x] = sc[SCAN_BLK - 1];
}

__global__ __launch_bounds__(128) void k_scanB(const unsigned* __restrict__ bsum,
                                               unsigned* __restrict__ boff)
{
    __shared__ unsigned s[128];
    int t = threadIdx.x;
    unsigned v = (t < NB) ? bsum[t] : 0u;
    s[t] = v;
    __syncthreads();
    for (int off = 1; off < 128; off <<= 1) {
        unsigned x = s[t];
        unsigned add = (t >= off) ? s[t - off] : 0u;
        __syncthreads();
        s[t] = x + add;
        __syncthreads();
    }
    if (t < NB) boff[t] = s[t] - v;
}

__global__ __launch_bounds__(SCAN_BLK) void k_scanC(unsigned* __restrict__ starts,
                                                    const unsigned* __restrict__ boff,
                                                    unsigned* __restrict__ cursor)
{
    int a = blockIdx.x * SCAN_BLK + threadIdx.x;
    if (a >= N_ATOMS) return;
    unsigned s = starts[a] + boff[blockIdx.x];
    starts[a] = s;
    cursor[a] = s;
}

// streaming reduce, f32x4 per lane: wave covers 16 rows/iter
__global__ __launch_bounds__(256) void k_reduce_stream(const unsigned* __restrict__ starts,
                                                       const unsigned* __restrict__ counts,
                                                       const float* __restrict__ svals,
                                                       float* __restrict__ p_sum)
{
    int a = blockIdx.x * 4 + (threadIdx.x >> 6);
    if (a >= N_ATOMS) return;
    int lane = threadIdx.x & 63;
    int c4 = lane & 3;          // quarter (ch 4*c4..4*c4+3)
    int q  = lane >> 2;         // row group 0..15
    unsigned n = counts[a], st = starts[a];
    f32x4 acc = {0.f, 0.f, 0.f, 0.f};
    for (unsigned k = q; k < n; k += 16)
        acc += *reinterpret_cast<const f32x4*>(svals + (size_t)(st + k) * W + c4*4);
#pragma unroll
    for (int off = 4; off < 64; off <<= 1) {
        acc[0] += __shfl_xor(acc[0], off);
        acc[1] += __shfl_xor(acc[1], off);
        acc[2] += __shfl_xor(acc[2], off);
        acc[3] += __shfl_xor(acc[3], off);
    }
    if (lane < 4)
        *reinterpret_cast<f32x4*>(p_sum + (size_t)a * W + lane*4) = acc;
}

// ---------------- pp_post
__global__ __launch_bounds__(256) void k_pp_post(
    const float* __restrict__ p_sum,
    const float* __restrict__ W0, const float* __restrict__ W1,
    float* __restrict__ p1_new)
{
    int a = blockIdx.x * 256 + threadIdx.x;
    if (a >= N_ATOMS) return;
    const float4* src = reinterpret_cast<const float4*>(p_sum + (size_t)a * W);
    float4 v0 = src[0], v1 = src[1], v2 = src[2], v3 = src[3];
    float x[W] = {v0.x,v0.y,v0.z,v0.w, v1.x,v1.y,v1.z,v1.w,
                  v2.x,v2.y,v2.z,v2.w, v3.x,v3.y,v3.z,v3.w};
    float h[W];
#pragma unroll
    for (int c = 0; c < W; ++c) h[c] = 0.0f;
#pragma unroll
    for (int k = 0; k < W; ++k)
#pragma unroll
        for (int c = 0; c < W; ++c) h[c] += x[k] * W0[k*W + c];
#pragma unroll
    for (int c = 0; c < W; ++c) h[c] = fast_tanh(h[c]);
    float y[W];
#pragma unroll
    for (int c = 0; c < W; ++c) y[c] = 0.0f;
#pragma unroll
    for (int k = 0; k < W; ++k)
#pragma unroll
        for (int c = 0; c < W; ++c) y[c] += h[k] * W1[k*W + c];
    float4* dst = reinterpret_cast<float4*>(p1_new + (size_t)a * W);
    dst[0] = make_float4(fast_tanh(y[0]),  fast_tanh(y[1]),  fast_tanh(y[2]),  fast_tanh(y[3]));
    dst[1] = make_float4(fast_tanh(y[4]),  fast_tanh(y[5]),  fast_tanh(y[6]),  fast_tanh(y[7]));
    dst[2] = make_float4(fast_tanh(y[8]),  fast_tanh(y[9]),  fast_tanh(y[10]), fast_tanh(y[11]));
    dst[3] = make_float4(fast_tanh(y[12]), fast_tanh(y[13]), fast_tanh(y[14]), fast_tanh(y[15]));
}

extern "C" void kernel_launch(void* const* d_in, const int* in_sizes, int n_in,
                              void* d_out, int out_size, void* d_ws, size_t ws_size,
                              hipStream_t stream) {
    const int*   ind2   = (const int*)d_in[0];
    const float* p1     = (const float*)d_in[1];
    const float* basis  = (const float*)d_in[2];
    const float* Wpre0  = (const float*)d_in[3];
    const float* bpre0  = (const float*)d_in[4];
    const float* Wpre1  = (const float*)d_in[5];
    const float* bpre1  = (const float*)d_in[6];
    const float* Wpi0   = (const float*)d_in[7];
    const float* bpi0   = (const float*)d_in[8];
    const float* Wpi1   = (const float*)d_in[9];
    const float* bpi1   = (const float*)d_in[10];
    const float* Wii0   = (const float*)d_in[11];
    const float* Wii1   = (const float*)d_in[12];
    const float* Wpost0 = (const float*)d_in[13];
    const float* Wpost1 = (const float*)d_in[14];

    float* out    = (float*)d_out;
    float* p1_new = out;                          // (N_ATOMS, W)
    float* i_pair = out + (size_t)N_ATOMS * W;    // (N_PAIRS, W)

    char* ws = (char*)d_ws;
    float*    ytop   = (float*)ws;                                ws += (size_t)N_ATOMS * W * 4;
    float*    ybot   = (float*)ws;                                ws += (size_t)N_ATOMS * W * 4;
    float*    p_sum  = (float*)ws;                                ws += (size_t)N_ATOMS * W * 4;
    unsigned* counts = (unsigned*)ws;                             ws += (size_t)N_ATOMS * 4;
    unsigned* starts = (unsigned*)ws;                             ws += (size_t)N_ATOMS * 4;
    unsigned* cursor = (unsigned*)ws;                             ws += (size_t)N_ATOMS * 4;
    unsigned* bsum   = (unsigned*)ws;                             ws += 1024 * 4;
    unsigned* boff   = (unsigned*)ws;                             ws += 1024 * 4;
    float*    svals  = (float*)ws;                                ws += (size_t)N_PAIRS * W * 4;
    unsigned* rank   = (unsigned*)ws;                             ws += (size_t)N_PAIRS * 4;

    int use_rank = (ws_size >= (size_t)(ws - (char*)d_ws));

    hipMemsetAsync(counts, 0, (size_t)N_ATOMS * sizeof(unsigned), stream);
    k_pp_pre<<<(N_ATOMS + 255) / 256, 256, 0, stream>>>(p1, Wpre0, bpre0, Wpre1, bpre1,
                                                        Wpi0, bpi0, ytop, ybot);
    k_count<<<(N_PAIRS / 2 + 255) / 256, 256, 0, stream>>>(ind2, counts, use_rank ? rank : cursor);
    k_scanA<<<NB, SCAN_BLK, 0, stream>>>(counts, starts, bsum);
    k_scanB<<<1, 128, 0, stream>>>(bsum, boff);
    k_scanC<<<NB, SCAN_BLK, 0, stream>>>(starts, boff, cursor);

    if (use_rank) {
        k_pair_mfma<1><<<2560, 256, 0, stream>>>(ind2, basis, ytop, ybot,
                                                 Wpi1, bpi1, Wii0, Wii1,
                                                 i_pair, starts, rank, cursor, svals);
    } else {
        k_pair_mfma<0><<<2560, 256, 0, stream>>>(ind2, basis, ytop, ybot,
                                                 Wpi1, bpi1, Wii0, Wii1,
                                                 i_pair, starts, rank, cursor, svals);
    }
    k_reduce_stream<<<(N_ATOMS + 3) / 4, 256, 0, stream>>>(starts, counts, svals, p_sum);
    k_pp_post<<<(N_ATOMS + 255) / 256, 256, 0, stream>>>(p_sum, Wpost0, Wpost1, p1_new);
}